// Round 10
// baseline (2949.995 us; speedup 1.0000x reference)
//
#include <hip/hip_runtime.h>
#include <math.h>

// Problem constants: E=1,000,000  R=1000  D=200  N_BATCH=50,000  N_TOTAL=100,000
#define DD     200
#define DD3    600
#define NBK    256     // buckets = chunk(r>>5, 32) * 8 + g(slot>>13, 8)
#define BCAP2  96      // binscatter LDS bin capacity (uint32)
#define FTHR   64      // flush threshold
#define ACH    1024    // accum staged entries per pass

typedef unsigned int   uint32;
typedef unsigned short uint16;

static __device__ inline float bf2f(uint16 u) {
    union { uint32 i; float f; } x; x.i = ((uint32)u) << 16; return x.f;
}
static __device__ inline uint16 f2bf(float f) {
    union { float f; uint32 i; } x; x.f = f;
    return (uint16)((x.i + 0x7FFFu + ((x.i >> 16) & 1u)) >> 16);
}
static __device__ inline float asf(uint32 u) {
    union { uint32 i; float f; } x; x.i = u; return x.f;
}
static __device__ inline uint32 packbf(float a, float b) {
    return (uint32)f2bf(a) | ((uint32)f2bf(b) << 16);
}

// ---------------- zero int counters ----------------
__global__ void zero_kernel(int* __restrict__ cnt, int n) {
    int stride = gridDim.x * blockDim.x;
    for (int i = blockIdx.x * blockDim.x + threadIdx.x; i < n; i += stride) cnt[i] = 0;
}

// ---------------- zero float buffer ----------------
__global__ void zerof_kernel(float* __restrict__ p, int n) {
    int stride = gridDim.x * blockDim.x;
    for (int i = blockIdx.x * blockDim.x + threadIdx.x; i < n; i += stride) p[i] = 0.f;
}

// -------- hist over 256 buckets: bucket = (r>>5)*8 + (slot>>13) --------
__launch_bounds__(256)
__global__ void hist224_kernel(const int* __restrict__ etype, const int* __restrict__ eidx,
                               int* __restrict__ gcnt, int E) {
    __shared__ int lc[NBK];
    const int tid = threadIdx.x;
    for (int i = tid; i < NBK; i += 256) lc[i] = 0;
    __syncthreads();
    int per = (E + gridDim.x - 1) / gridDim.x;
    int beg = blockIdx.x * per;
    int end = min(E, beg + per);
    for (int e = beg + tid; e < end; e += 256) {
        int r  = etype[e];
        int ch = r >> 5;
        int bS = (ch << 3) | (eidx[e] >> 13);
        int bD = (ch << 3) | (eidx[E + e] >> 13);
        atomicAdd(&lc[bS], 1);
        atomicAdd(&lc[bD], 1);
    }
    __syncthreads();
    for (int i = tid; i < NBK; i += 256)
        if (lc[i]) atomicAdd(&gcnt[i], lc[i]);
}

// ---- exclusive scan over 256 buckets (single block) ----
__launch_bounds__(256)
__global__ void scan224_kernel(const int* __restrict__ gcnt, int* __restrict__ offs,
                               int* __restrict__ gcur) {
    __shared__ int s[NBK];
    const int t = threadIdx.x;
    int v = gcnt[t];
    s[t] = v;
    for (int off = 1; off < NBK; off <<= 1) {
        __syncthreads();
        int tmp = (t >= off) ? s[t - off] : 0;
        __syncthreads();
        s[t] += tmp;
    }
    __syncthreads();
    int excl = s[t] - v;
    offs[t] = excl;
    gcur[t] = excl;
    if (t == NBK - 1) offs[NBK] = s[t];
}

// ---- radix-256 binscatter: LDS bins, coalesced flushes ----
// entry = ((2*(r&31)+side) << 16) | slot  (rs local to chunk)
__launch_bounds__(512)
__global__ void binscatter_kernel(const int* __restrict__ etype, const int* __restrict__ eidx,
                                  int* __restrict__ gcur, uint32* __restrict__ binned, int E) {
    __shared__ uint32 bb[NBK][BCAP2];   // 96 KB
    __shared__ int bcnt[NBK];
    const int tid  = threadIdx.x;       // 512
    const int wv   = tid >> 6;
    const int lane = tid & 63;
    for (int i = tid; i < NBK; i += 512) bcnt[i] = 0;
    __syncthreads();
    int per = (E + gridDim.x - 1) / gridDim.x;
    int beg = blockIdx.x * per;
    int end = min(E, beg + per);
    for (int base = beg; base < end; base += 512) {
        int e = base + tid;
        if (e < end) {
            int r  = etype[e];
            int sS = eidx[e];
            int sD = eidx[E + e];
            int ch = r >> 5;
            int rb = (r & 31) << 1;
            int bS = (ch << 3) | (sS >> 13);
            int bD = (ch << 3) | (sD >> 13);
            int p = atomicAdd(&bcnt[bS], 1);
            if (p < BCAP2) bb[bS][p] = ((uint32)rb << 16) | (uint32)sS;
            p = atomicAdd(&bcnt[bD], 1);
            if (p < BCAP2) bb[bD][p] = ((uint32)(rb + 1) << 16) | (uint32)sD;
        }
        __syncthreads();
        // flush bins >= FTHR; wave wv owns bins [wv*32, wv*32+32)
        for (int b = wv * 32; b < wv * 32 + 32; ++b) {
            int c = bcnt[b];
            if (c >= FTHR) {
                c = min(c, BCAP2);
                int pos = 0;
                if (lane == 0) pos = atomicAdd(&gcur[b], c);
                pos = __builtin_amdgcn_readfirstlane(pos);
                for (int i = lane; i < c; i += 64) binned[pos + i] = bb[b][i];
                if (lane == 0) bcnt[b] = 0;
            }
        }
        __syncthreads();
    }
    // final flush (any nonzero bin)
    for (int b = wv * 32; b < wv * 32 + 32; ++b) {
        int c = min(bcnt[b], BCAP2);
        if (c > 0) {
            int pos = 0;
            if (lane == 0) pos = atomicAdd(&gcur[b], c);
            pos = __builtin_amdgcn_readfirstlane(pos);
            for (int i = lane; i < c; i += 64) binned[pos + i] = bb[b][i];
        }
    }
}

// ---- fused prep: compact rows to bf16 + transpose both W matrices ----
__global__ void prep_kernel(const int* __restrict__ node_id, const float* __restrict__ emb,
                            uint32* __restrict__ cmp, int NB,
                            const float* __restrict__ A, const float* __restrict__ B,
                            float* __restrict__ TA, float* __restrict__ TB,
                            int rows, int cols) {
    int idx = blockIdx.x * blockDim.x + threadIdx.x;
    int nc = NB * 50;
    int nt = rows * cols;
    if (idx < nc) {
        int s = idx / 50, q = idx - s * 50;        // q in [0,50): dims 4q..4q+3
        int nid = node_id[s];
        float4 v = *(const float4*)(emb + (size_t)nid * DD + 4 * q);
        *(uint2*)(cmp + (size_t)s * 100 + 2 * q) = make_uint2(packbf(v.x, v.y), packbf(v.z, v.w));
    } else if (idx < nc + nt) {
        int k = idx - nc;
        int j = k / cols, d = k % cols;
        TA[d * rows + j] = A[k];
    } else if (idx < nc + 2 * nt) {
        int k = idx - nc - nt;
        int j = k / cols, d = k % cols;
        TB[d * rows + j] = B[k];
    }
}

// ---- accum: block = (g=bid&7, chunk=(bid>>3)&31, split=bid>>8) ----
// LDS fp32 accumulate, swizzled layout acc[rs][(d&3)*64 + (d>>2)] -> banks q%32 (2-way, free)
__launch_bounds__(512)
__global__ void accum_kernel(const uint32* __restrict__ binned, const uint32* __restrict__ cmp,
                             const int* __restrict__ offs,
                             float* __restrict__ xsumf, float* __restrict__ cntf) {
    __shared__ float  acc[64 * 256];   // 64 KB
    __shared__ float  acnt[64];
    __shared__ uint32 sl[ACH];         // 4 KB
    const int tid  = threadIdx.x;      // 512
    const int wv   = tid >> 6;
    const int lane = tid & 63;
    const int g    = blockIdx.x & 7;
    const int ch   = (blockIdx.x >> 3) & 31;
    const int sp   = blockIdx.x >> 8;  // 0/1
    const int bk   = (ch << 3) | g;

    for (int i = tid; i < 64 * 256; i += 512) acc[i] = 0.f;
    if (tid < 64) acnt[tid] = 0.f;
    __syncthreads();

    const int rb   = offs[bk];
    const int re   = offs[bk + 1];
    const int len  = re - rb;
    const int half = (len + 1) >> 1;
    const int beg  = rb + sp * half;
    const int end  = min(re, beg + half);
    const uint2* __restrict__ cmp2 = (const uint2*)cmp;

    for (int base = beg; base < end; base += ACH) {
        const int m = min(ACH, end - base);
        for (int i = tid; i < m; i += 512) sl[i] = binned[base + i];
        __syncthreads();
        int j = wv;
        for (; j + 8 < m; j += 16) {     // 2 independent gathers in flight per wave
            uint32 e0 = sl[j], e1 = sl[j + 8];
            int r0 = e0 >> 16, s0 = e0 & 0xFFFF;
            int r1 = e1 >> 16, s1 = e1 & 0xFFFF;
            if (lane < 50) {
                uint2 v0 = cmp2[s0 * 50 + lane];
                uint2 v1 = cmp2[s1 * 50 + lane];
                int b0 = r0 * 256 + lane, b1 = r1 * 256 + lane;
                atomicAdd(&acc[b0],       asf(v0.x << 16));
                atomicAdd(&acc[b0 + 64],  asf(v0.x & 0xFFFF0000u));
                atomicAdd(&acc[b0 + 128], asf(v0.y << 16));
                atomicAdd(&acc[b0 + 192], asf(v0.y & 0xFFFF0000u));
                atomicAdd(&acc[b1],       asf(v1.x << 16));
                atomicAdd(&acc[b1 + 64],  asf(v1.x & 0xFFFF0000u));
                atomicAdd(&acc[b1 + 128], asf(v1.y << 16));
                atomicAdd(&acc[b1 + 192], asf(v1.y & 0xFFFF0000u));
            } else if (lane == 50) {
                atomicAdd(&acnt[r0], 1.f);
                atomicAdd(&acnt[r1], 1.f);
            }
        }
        for (; j < m; j += 8) {
            uint32 e0 = sl[j];
            int r0 = e0 >> 16, s0 = e0 & 0xFFFF;
            if (lane < 50) {
                uint2 v0 = cmp2[s0 * 50 + lane];
                int b0 = r0 * 256 + lane;
                atomicAdd(&acc[b0],       asf(v0.x << 16));
                atomicAdd(&acc[b0 + 64],  asf(v0.x & 0xFFFF0000u));
                atomicAdd(&acc[b0 + 128], asf(v0.y << 16));
                atomicAdd(&acc[b0 + 192], asf(v0.y & 0xFFFF0000u));
            } else if (lane == 50) {
                atomicAdd(&acnt[r0], 1.f);
            }
        }
        __syncthreads();
    }

    // flush: acc[rsl][(d&3)*64 + (d>>2)] -> xsumf[(ch*64+rsl)*DD + d]
    for (int i = tid; i < 64 * DD; i += 512) {
        int rsl = i / DD, d = i - rsl * DD;
        float v = acc[rsl * 256 + (d & 3) * 64 + (d >> 2)];
        if (v != 0.f) atomicAdd(&xsumf[(size_t)(ch * 64 + rsl) * DD + d], v);
    }
    if (tid < 64) {
        float c = acnt[tid];
        if (c > 0.f) atomicAdd(&cntf[ch * 64 + tid], c);
    }
}

// -------- batched GEMV (8 relations/block) + GRU combine + write (fp32 sums) --------
__launch_bounds__(256)
__global__ void gemv_gru8f_kernel(const float* __restrict__ xsumf, // (R*2, D) fp32 sums
                                  const float* __restrict__ cntf,  // (R*2)
                                  const float* __restrict__ dyn,   // (R,1,D,2)
                                  const float* __restrict__ WT_ih, // (D,3D)
                                  const float* __restrict__ WT_hh,
                                  const float* __restrict__ b_ih,
                                  const float* __restrict__ b_hh,
                                  float* __restrict__ out) {       // (R,1,D,2)
    const int x    = blockIdx.x;      // relation octet
    const int side = blockIdx.y;
    const int tid  = threadIdx.x;

    __shared__ float xs[8][DD];
    __shared__ float hs[8][DD];
    __shared__ float gi[8][DD3];
    __shared__ float gh[8][DD3];

    #pragma unroll
    for (int rr = 0; rr < 8; ++rr) {
        int r  = x * 8 + rr;
        int rs = r * 2 + side;
        if (tid < DD) {
            float n = cntf[rs];
            xs[rr][tid] = (n > 0.f) ? xsumf[(size_t)rs * DD + tid] / n : 0.f;
            hs[rr][tid] = dyn[((size_t)r * DD + tid) * 2 + side];
        }
    }
    __syncthreads();

    {
        float aI0[8], aI1[8], aI2[8], aH0[8], aH1[8], aH2[8];
        #pragma unroll
        for (int rr = 0; rr < 8; ++rr) {
            aI0[rr] = aI1[rr] = aI2[rr] = 0.f;
            aH0[rr] = aH1[rr] = aH2[rr] = 0.f;
        }
        const bool has2 = tid < (DD3 - 512);   // tid < 88
        for (int k = 0; k < DD; ++k) {
            const float* rI = WT_ih + k * DD3;
            const float* rH = WT_hh + k * DD3;
            float wi0 = rI[tid], wi1 = rI[tid + 256];
            float wh0 = rH[tid], wh1 = rH[tid + 256];
            float wi2 = has2 ? rI[tid + 512] : 0.f;
            float wh2 = has2 ? rH[tid + 512] : 0.f;
            #pragma unroll
            for (int rr = 0; rr < 8; ++rr) {
                float xv = xs[rr][k];
                float hv = hs[rr][k];
                aI0[rr] = fmaf(xv, wi0, aI0[rr]);
                aI1[rr] = fmaf(xv, wi1, aI1[rr]);
                aI2[rr] = fmaf(xv, wi2, aI2[rr]);
                aH0[rr] = fmaf(hv, wh0, aH0[rr]);
                aH1[rr] = fmaf(hv, wh1, aH1[rr]);
                aH2[rr] = fmaf(hv, wh2, aH2[rr]);
            }
        }
        #pragma unroll
        for (int rr = 0; rr < 8; ++rr) {
            gi[rr][tid]       = aI0[rr] + b_ih[tid];
            gh[rr][tid]       = aH0[rr] + b_hh[tid];
            gi[rr][tid + 256] = aI1[rr] + b_ih[tid + 256];
            gh[rr][tid + 256] = aH1[rr] + b_hh[tid + 256];
            if (has2) {
                gi[rr][tid + 512] = aI2[rr] + b_ih[tid + 512];
                gh[rr][tid + 512] = aH2[rr] + b_hh[tid + 512];
            }
        }
    }
    __syncthreads();

    if (tid < DD) {
        #pragma unroll
        for (int rr = 0; rr < 8; ++rr) {
            int r = x * 8 + rr;
            float rg = 1.f / (1.f + __expf(-(gi[rr][tid] + gh[rr][tid])));
            float zz = 1.f / (1.f + __expf(-(gi[rr][DD + tid] + gh[rr][DD + tid])));
            float nn = tanhf(gi[rr][2 * DD + tid] + rg * gh[rr][2 * DD + tid]);
            out[((size_t)r * DD + tid) * 2 + side] = (1.f - zz) * nn + zz * hs[rr][tid];
        }
    }
}

// ================= fallback path (tiny ws): atomics into d_out ================
__global__ void hist_kernel(const int* __restrict__ etype, int* __restrict__ cnt,
                            int E, int R) {
    __shared__ int lc[1024];
    for (int i = threadIdx.x; i < R; i += blockDim.x) lc[i] = 0;
    __syncthreads();
    int stride = gridDim.x * blockDim.x;
    for (int i = blockIdx.x * blockDim.x + threadIdx.x; i < E; i += stride)
        atomicAdd(&lc[etype[i]], 1);
    __syncthreads();
    for (int i = threadIdx.x; i < R; i += blockDim.x)
        if (lc[i]) atomicAdd(&cnt[i], lc[i]);
}

__global__ void atomic_acc_kernel(const int* __restrict__ eidx, const int* __restrict__ etype,
                                  const int* __restrict__ node_id, const float* __restrict__ emb,
                                  float* __restrict__ acc, int E) {
    int gtid = blockIdx.x * blockDim.x + threadIdx.x;
    int wave = gtid >> 6, lane = gtid & 63;
    int nwaves = (gridDim.x * blockDim.x) >> 6;
    for (int e = wave; e < E; e += nwaves) {
        int r = etype[e];
        float* dst = acc + (size_t)r * DD * 2;
        for (int side = 0; side < 2; ++side) {
            int nid = node_id[eidx[(size_t)side * E + e]];
            const float* row = emb + (size_t)nid * DD;
            for (int d = lane; d < DD; d += 64)
                atomicAdd(&dst[d * 2 + side], row[d]);
        }
    }
}

__launch_bounds__(256)
__global__ void gru_inplace_kernel(const float* __restrict__ dyn, const float* __restrict__ W_ih,
                                   const float* __restrict__ W_hh, const float* __restrict__ b_ih,
                                   const float* __restrict__ b_hh, const int* __restrict__ cnt,
                                   float* __restrict__ out) {
    const int r = blockIdx.x, side = blockIdx.y, tid = threadIdx.x;
    __shared__ float xs[DD], hs[DD], gi[DD3], gh[DD3];
    if (tid < DD) {
        float s = out[((size_t)r * DD + tid) * 2 + side];
        int n = cnt[r];
        xs[tid] = (n > 0) ? s / (float)n : 0.f;
        hs[tid] = dyn[((size_t)r * DD + tid) * 2 + side];
    }
    __syncthreads();
    for (int jj = tid; jj < DD3; jj += 256) {
        float a = b_ih[jj], c = b_hh[jj];
        const float* rI = W_ih + (size_t)jj * DD;
        const float* rH = W_hh + (size_t)jj * DD;
        for (int k = 0; k < DD; ++k) { a = fmaf(xs[k], rI[k], a); c = fmaf(hs[k], rH[k], c); }
        gi[jj] = a; gh[jj] = c;
    }
    __syncthreads();
    if (tid < DD) {
        float rr = 1.f / (1.f + __expf(-(gi[tid] + gh[tid])));
        float zz = 1.f / (1.f + __expf(-(gi[DD + tid] + gh[DD + tid])));
        float nn = tanhf(gi[2 * DD + tid] + rr * gh[2 * DD + tid]);
        out[((size_t)r * DD + tid) * 2 + side] = (1.f - zz) * nn + zz * hs[tid];
    }
}

extern "C" void kernel_launch(void* const* d_in, const int* in_sizes, int n_in,
                              void* d_out, int out_size, void* d_ws, size_t ws_size,
                              hipStream_t stream) {
    const int*   eidx    = (const int*)d_in[0];
    const int*   etype   = (const int*)d_in[1];
    const int*   node_id = (const int*)d_in[2];
    const float* emb     = (const float*)d_in[3];
    const float* dyn     = (const float*)d_in[4];
    const float* W_ih    = (const float*)d_in[5];
    const float* W_hh    = (const float*)d_in[6];
    const float* b_ih    = (const float*)d_in[7];
    const float* b_hh    = (const float*)d_in[8];
    float*       out     = (float*)d_out;

    const int E   = in_sizes[1];
    const int NB  = in_sizes[2];               // 50,000
    const int D   = in_sizes[7] / 3;           // 200
    const int R   = in_sizes[4] / (2 * D);     // 1000
    const int D3  = 3 * D;                     // 600
    const int RS2 = R * 2;                     // 2000

    char* p = (char*)d_ws;
    auto take = [&](size_t bytes) { char* q = p; p += (bytes + 255) & ~(size_t)255; return q; };
    int*    gcnt   = (int*)   take((size_t)NBK * 4);
    int*    gcur   = (int*)   take((size_t)NBK * 4);
    int*    offs   = (int*)   take((size_t)(NBK + 1) * 4);
    uint32* binned = (uint32*)take((size_t)2 * E * 4);             // 8 MB
    uint32* cmp    = (uint32*)take((size_t)NB * 100 * 4);          // 20 MB
    float*  xsall  = (float*) take((size_t)(RS2 * DD + RS2) * 4);  // 1.61 MB
    float*  xsumf  = xsall;
    float*  cntf   = xsall + (size_t)RS2 * DD;
    size_t wt_bytes = ((size_t)D3 * D * 4 + 255) & ~(size_t)255;
    float* WT_ih = (float*)take(wt_bytes);
    float* WT_hh = (float*)take(wt_bytes);
    size_t need_full = (size_t)(p - (char*)d_ws);

    const bool fits = (ws_size >= need_full) && (NB <= 65535) && (R == 1000) &&
                      (D == 200) && ((R & 7) == 0);
    if (fits) {
        zero_kernel<<<1, 256, 0, stream>>>(gcnt, NBK);
        zerof_kernel<<<(RS2 * DD + RS2 + 255) / 256, 256, 0, stream>>>(xsall, RS2 * DD + RS2);
        hist224_kernel<<<256, 256, 0, stream>>>(etype, eidx, gcnt, E);
        scan224_kernel<<<1, NBK, 0, stream>>>(gcnt, offs, gcur);
        binscatter_kernel<<<256, 512, 0, stream>>>(etype, eidx, gcur, binned, E);
        int pw = (NB * 50 + 2 * D3 * D + 255) / 256;
        prep_kernel<<<pw, 256, 0, stream>>>(node_id, emb, cmp, NB,
                                            W_ih, W_hh, WT_ih, WT_hh, D3, D);
        accum_kernel<<<512, 512, 0, stream>>>(binned, cmp, offs, xsumf, cntf);
        dim3 grid(R / 8, 2);
        gemv_gru8f_kernel<<<grid, 256, 0, stream>>>(xsumf, cntf, dyn, WT_ih, WT_hh,
                                                    b_ih, b_hh, out);
    } else {
        int* cnt = (int*)d_ws;
        zero_kernel<<<32, 256, 0, stream>>>(cnt, R);
        hist_kernel<<<512, 256, 0, stream>>>(etype, cnt, E, R);
        zerof_kernel<<<(R * D * 2 + 255) / 256, 256, 0, stream>>>(out, R * D * 2);
        atomic_acc_kernel<<<2048, 256, 0, stream>>>(eidx, etype, node_id, emb, out, E);
        dim3 grid(R, 2);
        gru_inplace_kernel<<<grid, 256, 0, stream>>>(dyn, W_ih, W_hh, b_ih, b_hh, cnt, out);
    }
}

// Round 11
// 273.942 us; speedup vs baseline: 10.7687x; 10.7687x over previous
//
#include <hip/hip_runtime.h>
#include <math.h>

// Problem constants: E=1,000,000  R=1000  D=200  N_BATCH=50,000  N_TOTAL=100,000
#define DD     200
#define DD3    600
#define NBK    256     // radix buckets = chunk(r>>5, 32) * 8 + g(slot>>13, 8)
#define BCAP2  96      // binscatter LDS bin capacity (uint32)
#define FTHR   64      // binscatter flush threshold
#define SCAP   11264   // sortbucket LDS capacity (uint16): max bucket ~10.3k
#define CHUNK  1024    // partial7 slot-staging chunk

typedef unsigned int   uint32;
typedef unsigned short uint16;

static __device__ inline float bf2f(uint16 u) {
    union { uint32 i; float f; } x; x.i = ((uint32)u) << 16; return x.f;
}
static __device__ inline uint16 f2bf(float f) {
    union { float f; uint32 i; } x; x.f = f;
    return (uint16)((x.i + 0x7FFFu + ((x.i >> 16) & 1u)) >> 16);
}
static __device__ inline float asf(uint32 u) {
    union { uint32 i; float f; } x; x.i = u; return x.f;
}
static __device__ inline uint32 packbf(float a, float b) {
    return (uint32)f2bf(a) | ((uint32)f2bf(b) << 16);
}

// ---------------- zero int counters ----------------
__global__ void zero_kernel(int* __restrict__ cnt, int n) {
    int stride = gridDim.x * blockDim.x;
    for (int i = blockIdx.x * blockDim.x + threadIdx.x; i < n; i += stride) cnt[i] = 0;
}

// ---------------- zero float buffer ----------------
__global__ void zerof_kernel(float* __restrict__ p, int n) {
    int stride = gridDim.x * blockDim.x;
    for (int i = blockIdx.x * blockDim.x + threadIdx.x; i < n; i += stride) p[i] = 0.f;
}

// -------- hist over 256 buckets: bucket = (r>>5)*8 + (slot>>13) --------
__launch_bounds__(256)
__global__ void hist224_kernel(const int* __restrict__ etype, const int* __restrict__ eidx,
                               int* __restrict__ gcnt, int E) {
    __shared__ int lc[NBK];
    const int tid = threadIdx.x;
    for (int i = tid; i < NBK; i += 256) lc[i] = 0;
    __syncthreads();
    int per = (E + gridDim.x - 1) / gridDim.x;
    int beg = blockIdx.x * per;
    int end = min(E, beg + per);
    for (int e = beg + tid; e < end; e += 256) {
        int r  = etype[e];
        int ch = r >> 5;
        int bS = (ch << 3) | (eidx[e] >> 13);
        int bD = (ch << 3) | (eidx[E + e] >> 13);
        atomicAdd(&lc[bS], 1);
        atomicAdd(&lc[bD], 1);
    }
    __syncthreads();
    for (int i = tid; i < NBK; i += 256)
        if (lc[i]) atomicAdd(&gcnt[i], lc[i]);
}

// ---- exclusive scan over 256 buckets (single block) ----
__launch_bounds__(256)
__global__ void scan224_kernel(const int* __restrict__ gcnt, int* __restrict__ offs,
                               int* __restrict__ gcur) {
    __shared__ int s[NBK];
    const int t = threadIdx.x;
    int v = gcnt[t];
    s[t] = v;
    for (int off = 1; off < NBK; off <<= 1) {
        __syncthreads();
        int tmp = (t >= off) ? s[t - off] : 0;
        __syncthreads();
        s[t] += tmp;
    }
    __syncthreads();
    int excl = s[t] - v;
    offs[t] = excl;
    gcur[t] = excl;
    if (t == NBK - 1) offs[NBK] = s[t];
}

// ---- radix-256 binscatter: LDS bins, coalesced uint32 flushes ----
// entry = ((2*(r&31)+side) << 16) | slot
__launch_bounds__(512)
__global__ void binscatter_kernel(const int* __restrict__ etype, const int* __restrict__ eidx,
                                  int* __restrict__ gcur, uint32* __restrict__ binned, int E) {
    __shared__ uint32 bb[NBK][BCAP2];   // 96 KB
    __shared__ int bcnt[NBK];
    const int tid  = threadIdx.x;       // 512
    const int wv   = tid >> 6;
    const int lane = tid & 63;
    for (int i = tid; i < NBK; i += 512) bcnt[i] = 0;
    __syncthreads();
    int per = (E + gridDim.x - 1) / gridDim.x;
    int beg = blockIdx.x * per;
    int end = min(E, beg + per);
    for (int base = beg; base < end; base += 512) {
        int e = base + tid;
        if (e < end) {
            int r  = etype[e];
            int sS = eidx[e];
            int sD = eidx[E + e];
            int ch = r >> 5;
            int rb = (r & 31) << 1;
            int bS = (ch << 3) | (sS >> 13);
            int bD = (ch << 3) | (sD >> 13);
            int p = atomicAdd(&bcnt[bS], 1);
            if (p < BCAP2) bb[bS][p] = ((uint32)rb << 16) | (uint32)sS;
            p = atomicAdd(&bcnt[bD], 1);
            if (p < BCAP2) bb[bD][p] = ((uint32)(rb + 1) << 16) | (uint32)sD;
        }
        __syncthreads();
        for (int b = wv * 32; b < wv * 32 + 32; ++b) {
            int c = bcnt[b];
            if (c >= FTHR) {
                c = min(c, BCAP2);
                int pos = 0;
                if (lane == 0) pos = atomicAdd(&gcur[b], c);
                pos = __builtin_amdgcn_readfirstlane(pos);
                for (int i = lane; i < c; i += 64) binned[pos + i] = bb[b][i];
                if (lane == 0) bcnt[b] = 0;
            }
        }
        __syncthreads();
    }
    for (int b = wv * 32; b < wv * 32 + 32; ++b) {
        int c = min(bcnt[b], BCAP2);
        if (c > 0) {
            int pos = 0;
            if (lane == 0) pos = atomicAdd(&gcur[b], c);
            pos = __builtin_amdgcn_readfirstlane(pos);
            for (int i = lane; i < c; i += 64) binned[pos + i] = bb[b][i];
        }
    }
}

// ---- sortbucket: per bucket, 64-bin LDS counting sort -> coalesced list write ----
__launch_bounds__(512)
__global__ void sortbucket_kernel(const uint32* __restrict__ binned,
                                  const int* __restrict__ offs256,
                                  uint16* __restrict__ list, int* __restrict__ offs16k,
                                  int total) {
    __shared__ uint16 sorted[SCAP];      // 22.5 KB
    __shared__ int hist[64];
    __shared__ int cur[64];
    __shared__ int scn[65];
    const int bk  = blockIdx.x;
    const int tid = threadIdx.x;
    const int beg = offs256[bk];
    const int end = offs256[bk + 1];
    const int len = end - beg;

    if (tid < 64) hist[tid] = 0;
    __syncthreads();
    for (int i = tid; i < len; i += 512)
        atomicAdd(&hist[binned[beg + i] >> 16], 1);
    __syncthreads();
    if (tid == 0) {
        int acc = 0;
        #pragma unroll
        for (int q = 0; q < 64; ++q) { scn[q] = acc; cur[q] = acc; acc += hist[q]; }
        scn[64] = acc;
    }
    __syncthreads();
    if (tid < 64) offs16k[bk * 64 + tid] = beg + scn[tid];
    if (bk == 0 && tid == 64) offs16k[NBK * 64] = total;

    if (len <= SCAP) {
        for (int i = tid; i < len; i += 512) {
            uint32 e = binned[beg + i];
            int p = atomicAdd(&cur[e >> 16], 1);
            sorted[p] = (uint16)(e & 0xFFFF);
        }
        __syncthreads();
        for (int i = tid; i < len; i += 512) list[beg + i] = sorted[i];
    } else {
        // rare fallback: direct scatter (correct, slower)
        for (int i = tid; i < len; i += 512) {
            uint32 e = binned[beg + i];
            int p = atomicAdd(&cur[e >> 16], 1);
            list[beg + p] = (uint16)(e & 0xFFFF);
        }
    }
}

// ---- fused prep: compact rows to bf16 + transpose both W matrices ----
__global__ void prep_kernel(const int* __restrict__ node_id, const float* __restrict__ emb,
                            uint32* __restrict__ cmp, int NB,
                            const float* __restrict__ A, const float* __restrict__ B,
                            float* __restrict__ TA, float* __restrict__ TB,
                            int rows, int cols) {
    int idx = blockIdx.x * blockDim.x + threadIdx.x;
    int nc = NB * 50;
    int nt = rows * cols;
    if (idx < nc) {
        int s = idx / 50, q = idx - s * 50;        // q in [0,50): dims 4q..4q+3
        int nid = node_id[s];
        float4 v = *(const float4*)(emb + (size_t)nid * DD + 4 * q);
        *(uint2*)(cmp + (size_t)s * 100 + 2 * q) = make_uint2(packbf(v.x, v.y), packbf(v.z, v.w));
    } else if (idx < nc + nt) {
        int k = idx - nc;
        int j = k / cols, d = k % cols;
        TA[d * rows + j] = A[k];
    } else if (idx < nc + 2 * nt) {
        int k = idx - nc - nt;
        int j = k / cols, d = k % cols;
        TB[d * rows + j] = B[k];
    }
}

// -------- partial sums (R8-proven): bid -> g=bid&7 pins XCD-local cmp slice --------
// Full 400B rows, 2 entries/wave (lanes 0-24 entry A, 25-49 entry B, uint4/lane).
__launch_bounds__(256)
__global__ void partial7_kernel(const uint16* __restrict__ list,
                                const uint32* __restrict__ cmp,
                                const int* __restrict__ offs16k,
                                uint16* __restrict__ partial) {  // (16384, 200) bf16
    const int g    = blockIdx.x & 7;
    const int rest = blockIdx.x >> 3;     // ch*64 + rsl
    const int rsl  = rest & 63;
    const int ch   = rest >> 6;
    const int b16  = ((ch * 8 + g) << 6) | rsl;
    const int tid  = threadIdx.x;
    const int w    = tid >> 6;
    const int lane = tid & 63;
    const int sub  = lane / 25;        // 0: entry A, 1: entry B, 2: idle
    const int w25  = lane % 25;
    const int laneOff = w25 * 4;

    __shared__ uint16 sl[CHUNK];
    __shared__ float  red[8][DD];

    const int beg = offs16k[b16];
    const int end = offs16k[b16 + 1];

    float a0 = 0.f, a1 = 0.f, a2 = 0.f, a3 = 0.f, a4 = 0.f, a5 = 0.f, a6 = 0.f, a7 = 0.f;

    for (int base = beg; base < end; base += CHUNK) {
        const int m = min(CHUNK, end - base);
        for (int i = tid; i < m; i += 256) sl[i] = list[base + i];
        __syncthreads();
        if (sub < 2) {
            int i = w * 2 + sub;
            for (; i + 8 < m; i += 16) {       // 2 independent gathers in flight
                int s0 = sl[i];
                int s1 = sl[i + 8];
                uint4 v0 = *(const uint4*)(cmp + (size_t)s0 * 100 + laneOff);
                uint4 v1 = *(const uint4*)(cmp + (size_t)s1 * 100 + laneOff);
                a0 += asf(v0.x << 16) + asf(v1.x << 16);
                a1 += asf(v0.x & 0xFFFF0000u) + asf(v1.x & 0xFFFF0000u);
                a2 += asf(v0.y << 16) + asf(v1.y << 16);
                a3 += asf(v0.y & 0xFFFF0000u) + asf(v1.y & 0xFFFF0000u);
                a4 += asf(v0.z << 16) + asf(v1.z << 16);
                a5 += asf(v0.z & 0xFFFF0000u) + asf(v1.z & 0xFFFF0000u);
                a6 += asf(v0.w << 16) + asf(v1.w << 16);
                a7 += asf(v0.w & 0xFFFF0000u) + asf(v1.w & 0xFFFF0000u);
            }
            for (; i < m; i += 8) {
                int s0 = sl[i];
                uint4 v0 = *(const uint4*)(cmp + (size_t)s0 * 100 + laneOff);
                a0 += asf(v0.x << 16); a1 += asf(v0.x & 0xFFFF0000u);
                a2 += asf(v0.y << 16); a3 += asf(v0.y & 0xFFFF0000u);
                a4 += asf(v0.z << 16); a5 += asf(v0.z & 0xFFFF0000u);
                a6 += asf(v0.w << 16); a7 += asf(v0.w & 0xFFFF0000u);
            }
        }
        __syncthreads();
    }

    if (sub < 2) {
        int row = w * 2 + sub;
        int c = w25 * 8;
        red[row][c]     = a0; red[row][c + 1] = a1;
        red[row][c + 2] = a2; red[row][c + 3] = a3;
        red[row][c + 4] = a4; red[row][c + 5] = a5;
        red[row][c + 6] = a6; red[row][c + 7] = a7;
    }
    __syncthreads();

    if (tid < DD) {
        float s = 0.f;
        #pragma unroll
        for (int q = 0; q < 8; ++q) s += red[q][tid];
        partial[(size_t)b16 * DD + tid] = f2bf(s);
    }
}

// -------- batched GEMV (8 relations/block) + GRU combine + write --------
__launch_bounds__(256)
__global__ void gemv_gru8_kernel(const uint16* __restrict__ partial, // (16384,200) bf16
                                 const float* __restrict__ dyn,      // (R,1,D,2)
                                 const float* __restrict__ WT_ih,    // (D,3D)
                                 const float* __restrict__ WT_hh,
                                 const float* __restrict__ b_ih,
                                 const float* __restrict__ b_hh,
                                 const int* __restrict__ offs16k,
                                 float* __restrict__ out) {          // (R,1,D,2)
    const int x    = blockIdx.x;      // relation octet
    const int side = blockIdx.y;
    const int tid  = threadIdx.x;

    __shared__ float xs[8][DD];
    __shared__ float hs[8][DD];
    __shared__ float gi[8][DD3];
    __shared__ float gh[8][DD3];

    #pragma unroll
    for (int rr = 0; rr < 8; ++rr) {
        int r   = x * 8 + rr;
        int ch  = r >> 5;
        int rsl = ((r & 31) << 1) | side;
        if (tid < DD) {
            int n = 0;
            float s = 0.f;
            for (int g = 0; g < 8; ++g) {
                int b16 = ((ch * 8 + g) << 6) | rsl;
                int ng = offs16k[b16 + 1] - offs16k[b16];
                if (ng > 0) {
                    n += ng;
                    s += bf2f(partial[(size_t)b16 * DD + tid]);
                }
            }
            xs[rr][tid] = (n > 0) ? s / (float)n : 0.f;
            hs[rr][tid] = dyn[((size_t)r * DD + tid) * 2 + side];
        }
    }
    __syncthreads();

    {
        float aI0[8], aI1[8], aI2[8], aH0[8], aH1[8], aH2[8];
        #pragma unroll
        for (int rr = 0; rr < 8; ++rr) {
            aI0[rr] = aI1[rr] = aI2[rr] = 0.f;
            aH0[rr] = aH1[rr] = aH2[rr] = 0.f;
        }
        const bool has2 = tid < (DD3 - 512);   // tid < 88
        for (int k = 0; k < DD; ++k) {
            const float* rI = WT_ih + k * DD3;
            const float* rH = WT_hh + k * DD3;
            float wi0 = rI[tid], wi1 = rI[tid + 256];
            float wh0 = rH[tid], wh1 = rH[tid + 256];
            float wi2 = has2 ? rI[tid + 512] : 0.f;
            float wh2 = has2 ? rH[tid + 512] : 0.f;
            #pragma unroll
            for (int rr = 0; rr < 8; ++rr) {
                float xv = xs[rr][k];
                float hv = hs[rr][k];
                aI0[rr] = fmaf(xv, wi0, aI0[rr]);
                aI1[rr] = fmaf(xv, wi1, aI1[rr]);
                aI2[rr] = fmaf(xv, wi2, aI2[rr]);
                aH0[rr] = fmaf(hv, wh0, aH0[rr]);
                aH1[rr] = fmaf(hv, wh1, aH1[rr]);
                aH2[rr] = fmaf(hv, wh2, aH2[rr]);
            }
        }
        #pragma unroll
        for (int rr = 0; rr < 8; ++rr) {
            gi[rr][tid]       = aI0[rr] + b_ih[tid];
            gh[rr][tid]       = aH0[rr] + b_hh[tid];
            gi[rr][tid + 256] = aI1[rr] + b_ih[tid + 256];
            gh[rr][tid + 256] = aH1[rr] + b_hh[tid + 256];
            if (has2) {
                gi[rr][tid + 512] = aI2[rr] + b_ih[tid + 512];
                gh[rr][tid + 512] = aH2[rr] + b_hh[tid + 512];
            }
        }
    }
    __syncthreads();

    if (tid < DD) {
        #pragma unroll
        for (int rr = 0; rr < 8; ++rr) {
            int r = x * 8 + rr;
            float rg = 1.f / (1.f + __expf(-(gi[rr][tid] + gh[rr][tid])));
            float zz = 1.f / (1.f + __expf(-(gi[rr][DD + tid] + gh[rr][DD + tid])));
            float nn = tanhf(gi[rr][2 * DD + tid] + rg * gh[rr][2 * DD + tid]);
            out[((size_t)r * DD + tid) * 2 + side] = (1.f - zz) * nn + zz * hs[rr][tid];
        }
    }
}

// ================= fallback path (tiny ws): atomics into d_out ================
__global__ void hist_kernel(const int* __restrict__ etype, int* __restrict__ cnt,
                            int E, int R) {
    __shared__ int lc[1024];
    for (int i = threadIdx.x; i < R; i += blockDim.x) lc[i] = 0;
    __syncthreads();
    int stride = gridDim.x * blockDim.x;
    for (int i = blockIdx.x * blockDim.x + threadIdx.x; i < E; i += stride)
        atomicAdd(&lc[etype[i]], 1);
    __syncthreads();
    for (int i = threadIdx.x; i < R; i += blockDim.x)
        if (lc[i]) atomicAdd(&cnt[i], lc[i]);
}

__global__ void atomic_acc_kernel(const int* __restrict__ eidx, const int* __restrict__ etype,
                                  const int* __restrict__ node_id, const float* __restrict__ emb,
                                  float* __restrict__ acc, int E) {
    int gtid = blockIdx.x * blockDim.x + threadIdx.x;
    int wave = gtid >> 6, lane = gtid & 63;
    int nwaves = (gridDim.x * blockDim.x) >> 6;
    for (int e = wave; e < E; e += nwaves) {
        int r = etype[e];
        float* dst = acc + (size_t)r * DD * 2;
        for (int side = 0; side < 2; ++side) {
            int nid = node_id[eidx[(size_t)side * E + e]];
            const float* row = emb + (size_t)nid * DD;
            for (int d = lane; d < DD; d += 64)
                atomicAdd(&dst[d * 2 + side], row[d]);
        }
    }
}

__launch_bounds__(256)
__global__ void gru_inplace_kernel(const float* __restrict__ dyn, const float* __restrict__ W_ih,
                                   const float* __restrict__ W_hh, const float* __restrict__ b_ih,
                                   const float* __restrict__ b_hh, const int* __restrict__ cnt,
                                   float* __restrict__ out) {
    const int r = blockIdx.x, side = blockIdx.y, tid = threadIdx.x;
    __shared__ float xs[DD], hs[DD], gi[DD3], gh[DD3];
    if (tid < DD) {
        float s = out[((size_t)r * DD + tid) * 2 + side];
        int n = cnt[r];
        xs[tid] = (n > 0) ? s / (float)n : 0.f;
        hs[tid] = dyn[((size_t)r * DD + tid) * 2 + side];
    }
    __syncthreads();
    for (int jj = tid; jj < DD3; jj += 256) {
        float a = b_ih[jj], c = b_hh[jj];
        const float* rI = W_ih + (size_t)jj * DD;
        const float* rH = W_hh + (size_t)jj * DD;
        for (int k = 0; k < DD; ++k) { a = fmaf(xs[k], rI[k], a); c = fmaf(hs[k], rH[k], c); }
        gi[jj] = a; gh[jj] = c;
    }
    __syncthreads();
    if (tid < DD) {
        float rr = 1.f / (1.f + __expf(-(gi[tid] + gh[tid])));
        float zz = 1.f / (1.f + __expf(-(gi[DD + tid] + gh[DD + tid])));
        float nn = tanhf(gi[2 * DD + tid] + rr * gh[2 * DD + tid]);
        out[((size_t)r * DD + tid) * 2 + side] = (1.f - zz) * nn + zz * hs[tid];
    }
}

extern "C" void kernel_launch(void* const* d_in, const int* in_sizes, int n_in,
                              void* d_out, int out_size, void* d_ws, size_t ws_size,
                              hipStream_t stream) {
    const int*   eidx    = (const int*)d_in[0];
    const int*   etype   = (const int*)d_in[1];
    const int*   node_id = (const int*)d_in[2];
    const float* emb     = (const float*)d_in[3];
    const float* dyn     = (const float*)d_in[4];
    const float* W_ih    = (const float*)d_in[5];
    const float* W_hh    = (const float*)d_in[6];
    const float* b_ih    = (const float*)d_in[7];
    const float* b_hh    = (const float*)d_in[8];
    float*       out     = (float*)d_out;

    const int E   = in_sizes[1];
    const int NB  = in_sizes[2];               // 50,000
    const int D   = in_sizes[7] / 3;           // 200
    const int R   = in_sizes[4] / (2 * D);     // 1000
    const int D3  = 3 * D;                     // 600

    char* p = (char*)d_ws;
    auto take = [&](size_t bytes) { char* q = p; p += (bytes + 255) & ~(size_t)255; return q; };
    int*    gcnt    = (int*)   take((size_t)NBK * 4);
    int*    gcur    = (int*)   take((size_t)NBK * 4);
    int*    offs256 = (int*)   take((size_t)(NBK + 1) * 4);
    int*    offs16k = (int*)   take((size_t)(NBK * 64 + 1) * 4);  // 64 KB
    uint32* cmp     = (uint32*)take((size_t)NB * 100 * 4);        // 20 MB (binned overlays)
    uint16* list    = (uint16*)take((size_t)2 * E * 2);           // 4 MB
    uint16* partial = (uint16*)take((size_t)NBK * 64 * DD * 2);   // 6.55 MB
    size_t wt_bytes = ((size_t)D3 * D * 4 + 255) & ~(size_t)255;
    float* WT_ih = (float*)take(wt_bytes);
    float* WT_hh = (float*)take(wt_bytes);
    size_t need_full = (size_t)(p - (char*)d_ws);

    // binned (2E uint32 = 8 MB) overlays cmp (20 MB): binned dead after sortbucket,
    // prep (which writes cmp) launches after sortbucket on the same stream.
    uint32* binned = cmp;
    const bool binned_fits = ((size_t)2 * E * 4 <= (size_t)NB * 100 * 4);

    const bool fits = (ws_size >= need_full) && (NB <= 50000) && (R == 1000) &&
                      (D == 200) && ((R & 7) == 0) && binned_fits && (E <= 1000000);
    if (fits) {
        zero_kernel<<<1, 256, 0, stream>>>(gcnt, NBK);
        hist224_kernel<<<256, 256, 0, stream>>>(etype, eidx, gcnt, E);
        scan224_kernel<<<1, NBK, 0, stream>>>(gcnt, offs256, gcur);
        binscatter_kernel<<<256, 512, 0, stream>>>(etype, eidx, gcur, binned, E);
        sortbucket_kernel<<<NBK, 512, 0, stream>>>(binned, offs256, list, offs16k, 2 * E);
        int pw = (NB * 50 + 2 * D3 * D + 255) / 256;
        prep_kernel<<<pw, 256, 0, stream>>>(node_id, emb, cmp, NB,
                                            W_ih, W_hh, WT_ih, WT_hh, D3, D);
        partial7_kernel<<<NBK * 64, 256, 0, stream>>>(list, cmp, offs16k, partial);
        dim3 grid(R / 8, 2);
        gemv_gru8_kernel<<<grid, 256, 0, stream>>>(partial, dyn, WT_ih, WT_hh,
                                                   b_ih, b_hh, offs16k, out);
    } else {
        int* cnt = (int*)d_ws;
        zero_kernel<<<32, 256, 0, stream>>>(cnt, R);
        hist_kernel<<<512, 256, 0, stream>>>(etype, cnt, E, R);
        zerof_kernel<<<(R * D * 2 + 255) / 256, 256, 0, stream>>>(out, R * D * 2);
        atomic_acc_kernel<<<2048, 256, 0, stream>>>(eidx, etype, node_id, emb, out, E);
        dim3 grid(R, 2);
        gru_inplace_kernel<<<grid, 256, 0, stream>>>(dyn, W_ih, W_hh, b_ih, b_hh, cnt, out);
    }
}

// Round 12
// 210.841 us; speedup vs baseline: 13.9916x; 1.2993x over previous
//
#include <hip/hip_runtime.h>
#include <math.h>

// Problem constants: E=1,000,000  R=1000  D=200  N_BATCH=50,000  N_TOTAL=100,000
#define DD     200
#define DD3    600
#define NBK    256     // radix buckets = chunk(r>>5, 32) * 8 + g(slot>>13, 8)
#define GB     128     // sort grid blocks
#define SCH    8192    // blocksort entries per chunk (4096 edges)
#define SCAP   11264   // sortbucket LDS capacity (uint16)
#define CHUNK  1024    // partial7 slot-staging chunk

typedef unsigned int   uint32;
typedef unsigned short uint16;

static __device__ inline float bf2f(uint16 u) {
    union { uint32 i; float f; } x; x.i = ((uint32)u) << 16; return x.f;
}
static __device__ inline uint16 f2bf(float f) {
    union { float f; uint32 i; } x; x.f = f;
    return (uint16)((x.i + 0x7FFFu + ((x.i >> 16) & 1u)) >> 16);
}
static __device__ inline float asf(uint32 u) {
    union { uint32 i; float f; } x; x.i = u; return x.f;
}
static __device__ inline uint32 packbf(float a, float b) {
    return (uint32)f2bf(a) | ((uint32)f2bf(b) << 16);
}

// ---------------- zero int counters ----------------
__global__ void zero_kernel(int* __restrict__ cnt, int n) {
    int stride = gridDim.x * blockDim.x;
    for (int i = blockIdx.x * blockDim.x + threadIdx.x; i < n; i += stride) cnt[i] = 0;
}

// ---------------- zero float buffer ----------------
__global__ void zerof_kernel(float* __restrict__ p, int n) {
    int stride = gridDim.x * blockDim.x;
    for (int i = blockIdx.x * blockDim.x + threadIdx.x; i < n; i += stride) p[i] = 0.f;
}

// ---- pass A: per-block 256-bin histogram of its edge range -> boff[blk][bin] ----
__launch_bounds__(512)
__global__ void blockhist_kernel(const int* __restrict__ etype, const int* __restrict__ eidx,
                                 int* __restrict__ boff, int E) {
    __shared__ int lc[NBK];
    const int tid = threadIdx.x;
    if (tid < NBK) lc[tid] = 0;
    __syncthreads();
    int per = (E + GB - 1) / GB;
    int beg = blockIdx.x * per;
    int end = min(E, beg + per);
    for (int e = beg + tid; e < end; e += 512) {
        int r  = etype[e];
        int ch = r >> 5;
        atomicAdd(&lc[(ch << 3) | (eidx[e] >> 13)], 1);
        atomicAdd(&lc[(ch << 3) | (eidx[E + e] >> 13)], 1);
    }
    __syncthreads();
    if (tid < NBK) boff[blockIdx.x * NBK + tid] = lc[tid];
}

// ---- offset scan: boff counts -> exact global write positions (in place) ----
// thread t owns bin t: serial scan over GB blocks; then block-scan of bin totals.
__launch_bounds__(NBK)
__global__ void offscan_kernel(int* __restrict__ boff, int* __restrict__ offs256) {
    __shared__ int tot[NBK];
    __shared__ int s[NBK];
    const int t = threadIdx.x;
    int acc = 0;
    for (int b = 0; b < GB; ++b) {
        int v = boff[b * NBK + t];
        boff[b * NBK + t] = acc;
        acc += v;
    }
    tot[t] = acc;
    s[t] = acc;
    for (int off = 1; off < NBK; off <<= 1) {
        __syncthreads();
        int tmp = (t >= off) ? s[t - off] : 0;
        __syncthreads();
        s[t] += tmp;
    }
    __syncthreads();
    int base = s[t] - tot[t];
    offs256[t] = base;
    if (t == NBK - 1) offs256[NBK] = s[t];
    for (int b = 0; b < GB; ++b) boff[b * NBK + t] += base;
}

// ---- pass B: block counting sort, atomic-free coalesced run writes ----
// entry packed: [ch:5]<<24 | [rsl:6]<<16 | [slot:16];  key = (ch<<3)|(slot>>13)
__launch_bounds__(512)
__global__ void blocksort_kernel(const int* __restrict__ etype, const int* __restrict__ eidx,
                                 const int* __restrict__ boff, uint32* __restrict__ binned,
                                 int E) {
    __shared__ uint32 raw[SCH];        // 32 KB
    __shared__ uint32 srt[SCH];        // 32 KB
    __shared__ int lhist[NBK];
    __shared__ int loff[NBK + 1];
    __shared__ int lcur[NBK];
    __shared__ int bbase[NBK];
    const int tid  = threadIdx.x;
    const int wv   = tid >> 6;
    const int lane = tid & 63;

    if (tid < NBK) bbase[tid] = boff[blockIdx.x * NBK + tid];
    int per = (E + GB - 1) / GB;
    int ebeg = blockIdx.x * per;
    int eend = min(E, ebeg + per);

    for (int cb = ebeg; cb < eend; cb += SCH / 2) {
        const int ne = min(SCH / 2, eend - cb);
        const int m  = 2 * ne;
        if (tid < NBK) lhist[tid] = 0;
        __syncthreads();
        for (int i = tid; i < ne; i += 512) {
            int e  = cb + i;
            int r  = etype[e];
            int sS = eidx[e];
            int sD = eidx[E + e];
            int ch = r >> 5;
            int rb = (r & 31) << 1;
            raw[2 * i]     = ((uint32)ch << 24) | ((uint32)rb << 16) | (uint32)sS;
            raw[2 * i + 1] = ((uint32)ch << 24) | ((uint32)(rb + 1) << 16) | (uint32)sD;
            atomicAdd(&lhist[(ch << 3) | (sS >> 13)], 1);
            atomicAdd(&lhist[(ch << 3) | (sD >> 13)], 1);
        }
        __syncthreads();
        if (tid == 0) {
            int acc = 0;
            for (int q = 0; q < NBK; ++q) { loff[q] = acc; acc += lhist[q]; }
            loff[NBK] = acc;
        }
        __syncthreads();
        if (tid < NBK) lcur[tid] = loff[tid];
        __syncthreads();
        for (int i = tid; i < m; i += 512) {
            uint32 p = raw[i];
            int k = (int)((p >> 24) << 3) | (int)((p & 0xFFFFu) >> 13);
            int pos = atomicAdd(&lcur[k], 1);
            srt[pos] = p;
        }
        __syncthreads();
        // coalesced run writes: wave wv handles bins wv, wv+8, ...
        for (int b = wv; b < NBK; b += 8) {
            int lo = loff[b];
            int c  = loff[b + 1] - lo;
            if (c > 0) {
                int dst = bbase[b];
                for (int i = lane; i < c; i += 64) binned[dst + i] = srt[lo + i];
                if (lane == 0) bbase[b] = dst + c;
            }
        }
        __syncthreads();
    }
}

// ---- sortbucket: per bucket, 64-bin LDS counting sort by rsl -> coalesced list ----
__launch_bounds__(512)
__global__ void sortbucket_kernel(const uint32* __restrict__ binned,
                                  const int* __restrict__ offs256,
                                  uint16* __restrict__ list, int* __restrict__ offs16k,
                                  int total) {
    __shared__ uint16 sorted[SCAP];      // 22 KB
    __shared__ int hist[64];
    __shared__ int cur[64];
    __shared__ int scn[65];
    const int bk  = blockIdx.x;
    const int tid = threadIdx.x;
    const int beg = offs256[bk];
    const int end = offs256[bk + 1];
    const int len = end - beg;

    if (tid < 64) hist[tid] = 0;
    __syncthreads();
    for (int i = tid; i < len; i += 512)
        atomicAdd(&hist[(binned[beg + i] >> 16) & 63], 1);
    __syncthreads();
    if (tid == 0) {
        int acc = 0;
        #pragma unroll
        for (int q = 0; q < 64; ++q) { scn[q] = acc; cur[q] = acc; acc += hist[q]; }
        scn[64] = acc;
    }
    __syncthreads();
    if (tid < 64) offs16k[bk * 64 + tid] = beg + scn[tid];
    if (bk == 0 && tid == 64) offs16k[NBK * 64] = total;

    if (len <= SCAP) {
        for (int i = tid; i < len; i += 512) {
            uint32 e = binned[beg + i];
            int p = atomicAdd(&cur[(e >> 16) & 63], 1);
            sorted[p] = (uint16)(e & 0xFFFF);
        }
        __syncthreads();
        for (int i = tid; i < len; i += 512) list[beg + i] = sorted[i];
    } else {
        for (int i = tid; i < len; i += 512) {
            uint32 e = binned[beg + i];
            int p = atomicAdd(&cur[(e >> 16) & 63], 1);
            list[beg + p] = (uint16)(e & 0xFFFF);
        }
    }
}

// ---- fused prep: compact rows to bf16 + transpose both W matrices ----
__global__ void prep_kernel(const int* __restrict__ node_id, const float* __restrict__ emb,
                            uint32* __restrict__ cmp, int NB,
                            const float* __restrict__ A, const float* __restrict__ B,
                            float* __restrict__ TA, float* __restrict__ TB,
                            int rows, int cols) {
    int idx = blockIdx.x * blockDim.x + threadIdx.x;
    int nc = NB * 50;
    int nt = rows * cols;
    if (idx < nc) {
        int s = idx / 50, q = idx - s * 50;        // q in [0,50): dims 4q..4q+3
        int nid = node_id[s];
        float4 v = *(const float4*)(emb + (size_t)nid * DD + 4 * q);
        *(uint2*)(cmp + (size_t)s * 100 + 2 * q) = make_uint2(packbf(v.x, v.y), packbf(v.z, v.w));
    } else if (idx < nc + nt) {
        int k = idx - nc;
        int j = k / cols, d = k % cols;
        TA[d * rows + j] = A[k];
    } else if (idx < nc + 2 * nt) {
        int k = idx - nc - nt;
        int j = k / cols, d = k % cols;
        TB[d * rows + j] = B[k];
    }
}

// -------- partial sums (R8-proven): bid&7 = g pins XCD-local cmp slice --------
// Full 400B rows, 2 entries/wave (lanes 0-24 entry A, 25-49 entry B, uint4/lane).
__launch_bounds__(256)
__global__ void partial7_kernel(const uint16* __restrict__ list,
                                const uint32* __restrict__ cmp,
                                const int* __restrict__ offs16k,
                                uint16* __restrict__ partial) {  // (16384, 200) bf16
    const int g    = blockIdx.x & 7;
    const int rest = blockIdx.x >> 3;     // ch*64 + rsl
    const int rsl  = rest & 63;
    const int ch   = rest >> 6;
    const int b16  = ((ch * 8 + g) << 6) | rsl;
    const int tid  = threadIdx.x;
    const int w    = tid >> 6;
    const int lane = tid & 63;
    const int sub  = lane / 25;        // 0: entry A, 1: entry B, 2: idle
    const int w25  = lane % 25;
    const int laneOff = w25 * 4;

    __shared__ uint16 sl[CHUNK];
    __shared__ float  red[8][DD];

    const int beg = offs16k[b16];
    const int end = offs16k[b16 + 1];

    float a0 = 0.f, a1 = 0.f, a2 = 0.f, a3 = 0.f, a4 = 0.f, a5 = 0.f, a6 = 0.f, a7 = 0.f;

    for (int base = beg; base < end; base += CHUNK) {
        const int m = min(CHUNK, end - base);
        for (int i = tid; i < m; i += 256) sl[i] = list[base + i];
        __syncthreads();
        if (sub < 2) {
            int i = w * 2 + sub;
            for (; i + 8 < m; i += 16) {       // 2 independent gathers in flight
                int s0 = sl[i];
                int s1 = sl[i + 8];
                uint4 v0 = *(const uint4*)(cmp + (size_t)s0 * 100 + laneOff);
                uint4 v1 = *(const uint4*)(cmp + (size_t)s1 * 100 + laneOff);
                a0 += asf(v0.x << 16) + asf(v1.x << 16);
                a1 += asf(v0.x & 0xFFFF0000u) + asf(v1.x & 0xFFFF0000u);
                a2 += asf(v0.y << 16) + asf(v1.y << 16);
                a3 += asf(v0.y & 0xFFFF0000u) + asf(v1.y & 0xFFFF0000u);
                a4 += asf(v0.z << 16) + asf(v1.z << 16);
                a5 += asf(v0.z & 0xFFFF0000u) + asf(v1.z & 0xFFFF0000u);
                a6 += asf(v0.w << 16) + asf(v1.w << 16);
                a7 += asf(v0.w & 0xFFFF0000u) + asf(v1.w & 0xFFFF0000u);
            }
            for (; i < m; i += 8) {
                int s0 = sl[i];
                uint4 v0 = *(const uint4*)(cmp + (size_t)s0 * 100 + laneOff);
                a0 += asf(v0.x << 16); a1 += asf(v0.x & 0xFFFF0000u);
                a2 += asf(v0.y << 16); a3 += asf(v0.y & 0xFFFF0000u);
                a4 += asf(v0.z << 16); a5 += asf(v0.z & 0xFFFF0000u);
                a6 += asf(v0.w << 16); a7 += asf(v0.w & 0xFFFF0000u);
            }
        }
        __syncthreads();
    }

    if (sub < 2) {
        int row = w * 2 + sub;
        int c = w25 * 8;
        red[row][c]     = a0; red[row][c + 1] = a1;
        red[row][c + 2] = a2; red[row][c + 3] = a3;
        red[row][c + 4] = a4; red[row][c + 5] = a5;
        red[row][c + 6] = a6; red[row][c + 7] = a7;
    }
    __syncthreads();

    if (tid < DD) {
        float s = 0.f;
        #pragma unroll
        for (int q = 0; q < 8; ++q) s += red[q][tid];
        partial[(size_t)b16 * DD + tid] = f2bf(s);
    }
}

// -------- batched GEMV (8 relations/block) + GRU combine + write --------
__launch_bounds__(256)
__global__ void gemv_gru8_kernel(const uint16* __restrict__ partial, // (16384,200) bf16
                                 const float* __restrict__ dyn,      // (R,1,D,2)
                                 const float* __restrict__ WT_ih,    // (D,3D)
                                 const float* __restrict__ WT_hh,
                                 const float* __restrict__ b_ih,
                                 const float* __restrict__ b_hh,
                                 const int* __restrict__ offs16k,
                                 float* __restrict__ out) {          // (R,1,D,2)
    const int x    = blockIdx.x;      // relation octet
    const int side = blockIdx.y;
    const int tid  = threadIdx.x;

    __shared__ float xs[8][DD];
    __shared__ float hs[8][DD];
    __shared__ float gi[8][DD3];
    __shared__ float gh[8][DD3];

    #pragma unroll
    for (int rr = 0; rr < 8; ++rr) {
        int r   = x * 8 + rr;
        int ch  = r >> 5;
        int rsl = ((r & 31) << 1) | side;
        if (tid < DD) {
            int n = 0;
            float s = 0.f;
            for (int g = 0; g < 8; ++g) {
                int b16 = ((ch * 8 + g) << 6) | rsl;
                int ng = offs16k[b16 + 1] - offs16k[b16];
                if (ng > 0) {
                    n += ng;
                    s += bf2f(partial[(size_t)b16 * DD + tid]);
                }
            }
            xs[rr][tid] = (n > 0) ? s / (float)n : 0.f;
            hs[rr][tid] = dyn[((size_t)r * DD + tid) * 2 + side];
        }
    }
    __syncthreads();

    {
        float aI0[8], aI1[8], aI2[8], aH0[8], aH1[8], aH2[8];
        #pragma unroll
        for (int rr = 0; rr < 8; ++rr) {
            aI0[rr] = aI1[rr] = aI2[rr] = 0.f;
            aH0[rr] = aH1[rr] = aH2[rr] = 0.f;
        }
        const bool has2 = tid < (DD3 - 512);   // tid < 88
        for (int k = 0; k < DD; ++k) {
            const float* rI = WT_ih + k * DD3;
            const float* rH = WT_hh + k * DD3;
            float wi0 = rI[tid], wi1 = rI[tid + 256];
            float wh0 = rH[tid], wh1 = rH[tid + 256];
            float wi2 = has2 ? rI[tid + 512] : 0.f;
            float wh2 = has2 ? rH[tid + 512] : 0.f;
            #pragma unroll
            for (int rr = 0; rr < 8; ++rr) {
                float xv = xs[rr][k];
                float hv = hs[rr][k];
                aI0[rr] = fmaf(xv, wi0, aI0[rr]);
                aI1[rr] = fmaf(xv, wi1, aI1[rr]);
                aI2[rr] = fmaf(xv, wi2, aI2[rr]);
                aH0[rr] = fmaf(hv, wh0, aH0[rr]);
                aH1[rr] = fmaf(hv, wh1, aH1[rr]);
                aH2[rr] = fmaf(hv, wh2, aH2[rr]);
            }
        }
        #pragma unroll
        for (int rr = 0; rr < 8; ++rr) {
            gi[rr][tid]       = aI0[rr] + b_ih[tid];
            gh[rr][tid]       = aH0[rr] + b_hh[tid];
            gi[rr][tid + 256] = aI1[rr] + b_ih[tid + 256];
            gh[rr][tid + 256] = aH1[rr] + b_hh[tid + 256];
            if (has2) {
                gi[rr][tid + 512] = aI2[rr] + b_ih[tid + 512];
                gh[rr][tid + 512] = aH2[rr] + b_hh[tid + 512];
            }
        }
    }
    __syncthreads();

    if (tid < DD) {
        #pragma unroll
        for (int rr = 0; rr < 8; ++rr) {
            int r = x * 8 + rr;
            float rg = 1.f / (1.f + __expf(-(gi[rr][tid] + gh[rr][tid])));
            float zz = 1.f / (1.f + __expf(-(gi[rr][DD + tid] + gh[rr][DD + tid])));
            float nn = tanhf(gi[rr][2 * DD + tid] + rg * gh[rr][2 * DD + tid]);
            out[((size_t)r * DD + tid) * 2 + side] = (1.f - zz) * nn + zz * hs[rr][tid];
        }
    }
}

// ================= fallback path (tiny ws): atomics into d_out ================
__global__ void hist_kernel(const int* __restrict__ etype, int* __restrict__ cnt,
                            int E, int R) {
    __shared__ int lc[1024];
    for (int i = threadIdx.x; i < R; i += blockDim.x) lc[i] = 0;
    __syncthreads();
    int stride = gridDim.x * blockDim.x;
    for (int i = blockIdx.x * blockDim.x + threadIdx.x; i < E; i += stride)
        atomicAdd(&lc[etype[i]], 1);
    __syncthreads();
    for (int i = threadIdx.x; i < R; i += blockDim.x)
        if (lc[i]) atomicAdd(&cnt[i], lc[i]);
}

__global__ void atomic_acc_kernel(const int* __restrict__ eidx, const int* __restrict__ etype,
                                  const int* __restrict__ node_id, const float* __restrict__ emb,
                                  float* __restrict__ acc, int E) {
    int gtid = blockIdx.x * blockDim.x + threadIdx.x;
    int wave = gtid >> 6, lane = gtid & 63;
    int nwaves = (gridDim.x * blockDim.x) >> 6;
    for (int e = wave; e < E; e += nwaves) {
        int r = etype[e];
        float* dst = acc + (size_t)r * DD * 2;
        for (int side = 0; side < 2; ++side) {
            int nid = node_id[eidx[(size_t)side * E + e]];
            const float* row = emb + (size_t)nid * DD;
            for (int d = lane; d < DD; d += 64)
                atomicAdd(&dst[d * 2 + side], row[d]);
        }
    }
}

__launch_bounds__(256)
__global__ void gru_inplace_kernel(const float* __restrict__ dyn, const float* __restrict__ W_ih,
                                   const float* __restrict__ W_hh, const float* __restrict__ b_ih,
                                   const float* __restrict__ b_hh, const int* __restrict__ cnt,
                                   float* __restrict__ out) {
    const int r = blockIdx.x, side = blockIdx.y, tid = threadIdx.x;
    __shared__ float xs[DD], hs[DD], gi[DD3], gh[DD3];
    if (tid < DD) {
        float s = out[((size_t)r * DD + tid) * 2 + side];
        int n = cnt[r];
        xs[tid] = (n > 0) ? s / (float)n : 0.f;
        hs[tid] = dyn[((size_t)r * DD + tid) * 2 + side];
    }
    __syncthreads();
    for (int jj = tid; jj < DD3; jj += 256) {
        float a = b_ih[jj], c = b_hh[jj];
        const float* rI = W_ih + (size_t)jj * DD;
        const float* rH = W_hh + (size_t)jj * DD;
        for (int k = 0; k < DD; ++k) { a = fmaf(xs[k], rI[k], a); c = fmaf(hs[k], rH[k], c); }
        gi[jj] = a; gh[jj] = c;
    }
    __syncthreads();
    if (tid < DD) {
        float rr = 1.f / (1.f + __expf(-(gi[tid] + gh[tid])));
        float zz = 1.f / (1.f + __expf(-(gi[DD + tid] + gh[DD + tid])));
        float nn = tanhf(gi[2 * DD + tid] + rr * gh[2 * DD + tid]);
        out[((size_t)r * DD + tid) * 2 + side] = (1.f - zz) * nn + zz * hs[tid];
    }
}

extern "C" void kernel_launch(void* const* d_in, const int* in_sizes, int n_in,
                              void* d_out, int out_size, void* d_ws, size_t ws_size,
                              hipStream_t stream) {
    const int*   eidx    = (const int*)d_in[0];
    const int*   etype   = (const int*)d_in[1];
    const int*   node_id = (const int*)d_in[2];
    const float* emb     = (const float*)d_in[3];
    const float* dyn     = (const float*)d_in[4];
    const float* W_ih    = (const float*)d_in[5];
    const float* W_hh    = (const float*)d_in[6];
    const float* b_ih    = (const float*)d_in[7];
    const float* b_hh    = (const float*)d_in[8];
    float*       out     = (float*)d_out;

    const int E   = in_sizes[1];
    const int NB  = in_sizes[2];               // 50,000
    const int D   = in_sizes[7] / 3;           // 200
    const int R   = in_sizes[4] / (2 * D);     // 1000
    const int D3  = 3 * D;                     // 600

    char* p = (char*)d_ws;
    auto take = [&](size_t bytes) { char* q = p; p += (bytes + 255) & ~(size_t)255; return q; };
    int*    boff    = (int*)   take((size_t)GB * NBK * 4);        // 128 KB
    int*    offs256 = (int*)   take((size_t)(NBK + 1) * 4);
    int*    offs16k = (int*)   take((size_t)(NBK * 64 + 1) * 4);  // 64 KB
    uint32* cmp     = (uint32*)take((size_t)NB * 100 * 4);        // 20 MB (binned overlays)
    uint16* list    = (uint16*)take((size_t)2 * E * 2);           // 4 MB
    uint16* partial = (uint16*)take((size_t)NBK * 64 * DD * 2);   // 6.55 MB
    size_t wt_bytes = ((size_t)D3 * D * 4 + 255) & ~(size_t)255;
    float* WT_ih = (float*)take(wt_bytes);
    float* WT_hh = (float*)take(wt_bytes);
    size_t need_full = (size_t)(p - (char*)d_ws);

    // binned (2E uint32 = 8 MB) overlays cmp (20 MB): binned dead after sortbucket,
    // prep (which writes cmp) launches after sortbucket on the same stream.
    uint32* binned = cmp;
    const bool binned_fits = ((size_t)2 * E * 4 <= (size_t)NB * 100 * 4);

    const bool fits = (ws_size >= need_full) && (NB <= 50000) && (R == 1000) &&
                      (D == 200) && ((R & 7) == 0) && binned_fits && (E <= 1000000);
    if (fits) {
        blockhist_kernel<<<GB, 512, 0, stream>>>(etype, eidx, boff, E);
        offscan_kernel<<<1, NBK, 0, stream>>>(boff, offs256);
        blocksort_kernel<<<GB, 512, 0, stream>>>(etype, eidx, boff, binned, E);
        sortbucket_kernel<<<NBK, 512, 0, stream>>>(binned, offs256, list, offs16k, 2 * E);
        int pw = (NB * 50 + 2 * D3 * D + 255) / 256;
        prep_kernel<<<pw, 256, 0, stream>>>(node_id, emb, cmp, NB,
                                            W_ih, W_hh, WT_ih, WT_hh, D3, D);
        partial7_kernel<<<NBK * 64, 256, 0, stream>>>(list, cmp, offs16k, partial);
        dim3 grid(R / 8, 2);
        gemv_gru8_kernel<<<grid, 256, 0, stream>>>(partial, dyn, WT_ih, WT_hh,
                                                   b_ih, b_hh, offs16k, out);
    } else {
        int* cnt = (int*)d_ws;
        zero_kernel<<<32, 256, 0, stream>>>(cnt, R);
        hist_kernel<<<512, 256, 0, stream>>>(etype, cnt, E, R);
        zerof_kernel<<<(R * D * 2 + 255) / 256, 256, 0, stream>>>(out, R * D * 2);
        atomic_acc_kernel<<<2048, 256, 0, stream>>>(eidx, etype, node_id, emb, out, E);
        dim3 grid(R, 2);
        gru_inplace_kernel<<<grid, 256, 0, stream>>>(dyn, W_ih, W_hh, b_ih, b_hh, cnt, out);
    }
}